// Round 1
// baseline (550.302 us; speedup 1.0000x reference)
//
#include <hip/hip_runtime.h>
#include <math.h>

// Problem constants
#define LEN_Q 13294
#define NFRAMES 2
#define MTOT (LEN_Q * NFRAMES)   // 26588
#define DMODEL 256
#define HEADS 8
#define DH 32
#define LEVELS 4
#define POINTS 4

// ---------------------------------------------------------------------------
// f32 GEMM: C[M,N] = A[M,K] @ B[K,N] + bias[N]
// BM=128, BN=64, BK=16, 256 threads, 8x4 microtile per thread.
// ---------------------------------------------------------------------------
__global__ __launch_bounds__(256, 2) void gemm_bias(
    const float* __restrict__ A, const float* __restrict__ B,
    const float* __restrict__ bias, float* __restrict__ C,
    int M, int N, int K)
{
    constexpr int BM = 128, BN = 64, BK = 16;
    __shared__ float As[BK][BM + 4];   // transposed A tile, +4 pad keeps f4 align & kills write conflicts
    __shared__ float Bs[BK][BN];

    const int tid = threadIdx.x;
    const int tx = tid & 15;   // N direction: 16 x 4 = 64
    const int ty = tid >> 4;   // M direction: 16 x 8 = 128
    const int m0 = blockIdx.y * BM;
    const int n0 = blockIdx.x * BN;

    float acc[8][4];
    #pragma unroll
    for (int i = 0; i < 8; ++i)
        #pragma unroll
        for (int j = 0; j < 4; ++j) acc[i][j] = 0.f;

    const int a_row0 = tid >> 2;         // 0..63 (second chunk +64)
    const int a_col  = (tid & 3) * 4;    // 0,4,8,12
    const int b_row  = tid >> 4;         // 0..15
    const int b_col  = (tid & 15) * 4;   // 0..60

    for (int k0 = 0; k0 < K; k0 += BK) {
        #pragma unroll
        for (int qq = 0; qq < 2; ++qq) {
            int rowi = a_row0 + qq * 64;
            int am = m0 + rowi;
            float4 av = make_float4(0.f, 0.f, 0.f, 0.f);
            if (am < M) av = *(const float4*)(A + (size_t)am * K + k0 + a_col);
            As[a_col + 0][rowi] = av.x;
            As[a_col + 1][rowi] = av.y;
            As[a_col + 2][rowi] = av.z;
            As[a_col + 3][rowi] = av.w;
        }
        float4 bv4 = *(const float4*)(B + (size_t)(k0 + b_row) * N + n0 + b_col);
        *(float4*)&Bs[b_row][b_col] = bv4;
        __syncthreads();

        #pragma unroll
        for (int k = 0; k < BK; ++k) {
            float4 a0 = *(const float4*)&As[k][ty * 8];
            float4 a1 = *(const float4*)&As[k][ty * 8 + 4];
            float4 b4 = *(const float4*)&Bs[k][tx * 4];
            float a[8] = {a0.x, a0.y, a0.z, a0.w, a1.x, a1.y, a1.z, a1.w};
            float b[4] = {b4.x, b4.y, b4.z, b4.w};
            #pragma unroll
            for (int i = 0; i < 8; ++i)
                #pragma unroll
                for (int j = 0; j < 4; ++j)
                    acc[i][j] = fmaf(a[i], b[j], acc[i][j]);
        }
        __syncthreads();
    }

    float4 bb = *(const float4*)(bias + n0 + tx * 4);
    #pragma unroll
    for (int i = 0; i < 8; ++i) {
        int m = m0 + ty * 8 + i;
        if (m < M) {
            float4 o;
            o.x = acc[i][0] + bb.x;
            o.y = acc[i][1] + bb.y;
            o.z = acc[i][2] + bb.z;
            o.w = acc[i][3] + bb.w;
            *(float4*)(C + (size_t)m * N + n0 + tx * 4) = o;
        }
    }
}

// ---------------------------------------------------------------------------
// Sampling kernel: one block (256 threads) per (frame, query) row.
// Thread t: head h = t>>5, channel d = t&31 (global channel = t).
// Phases: load attn/loc -> softmax -> per-(h,l,p) corner idx/weight precompute
//         -> branch-free gather (weights are 0 for invalid corners, indices
//         clamped in-bounds, matching reference semantics exactly).
// ---------------------------------------------------------------------------
__global__ __launch_bounds__(256) void sample_kernel(
    const float* __restrict__ value,   // [MTOT, 256]  (frame-major rows)
    const float* __restrict__ off,     // [MTOT, 256]
    const float* __restrict__ attn,    // [MTOT, 128]
    const float* __restrict__ refpts,  // [LEN_Q, LEVELS, 2]
    const int*   __restrict__ spatial, // [LEVELS, 2]  (H, W)
    const int*   __restrict__ lsi,     // [LEVELS]
    float* __restrict__ samp)          // [MTOT, 256]
{
    const int row = blockIdx.x;              // 0..MTOT-1
    const int frame = row >= LEN_Q ? 1 : 0;  // NFRAMES == 2
    const int q = row - frame * LEN_Q;
    const int t = threadIdx.x;

    __shared__ float attn_s[HEADS][16];
    __shared__ float loc_s[HEADS][16][2];
    __shared__ float w_s[HEADS][16][4];
    __shared__ int   idx_s[HEADS][16][4];
    __shared__ int   sp_s[LEVELS][2];
    __shared__ int   lsi_s[LEVELS];

    // ---- phase 1: loads ----
    if (t < 8) sp_s[t >> 1][t & 1] = spatial[t];
    if (t < 4) lsi_s[t] = lsi[t];
    if (t < 128) attn_s[t >> 4][t & 15] = attn[(size_t)row * 128 + t];
    {
        // t encodes ((h*4 + l)*4 + p)*2 + c
        int c = t & 1;
        int l = (t >> 3) & 3;
        int h = t >> 5;
        int lp = (t >> 1) & 15;           // l*4 + p
        float o = off[(size_t)row * 256 + t];
        float r = refpts[((size_t)q * LEVELS + l) * 2 + c];
        // norm: c==0 -> W = spatial[l][1], c==1 -> H = spatial[l][0]
        int dim = spatial[l * 2 + (c == 0 ? 1 : 0)];
        loc_s[h][lp][c] = r + o / (float)dim;
    }
    __syncthreads();

    // ---- phase 2: softmax per head over 16 (l,p) ----
    if (t < 8) {
        float m = attn_s[t][0];
        #pragma unroll
        for (int i = 1; i < 16; ++i) m = fmaxf(m, attn_s[t][i]);
        float e[16];
        float s = 0.f;
        #pragma unroll
        for (int i = 0; i < 16; ++i) { e[i] = __expf(attn_s[t][i] - m); s += e[i]; }
        float inv = 1.f / s;
        #pragma unroll
        for (int i = 0; i < 16; ++i) attn_s[t][i] = e[i] * inv;
    }
    __syncthreads();

    // ---- phase 3: per (h, l, p) corner index + weight precompute ----
    if (t < 128) {
        int h = t >> 4;
        int lp = t & 15;
        int l = lp >> 2;
        int Hl = sp_s[l][0], Wl = sp_s[l][1];
        int start = lsi_s[l];
        float w = attn_s[h][lp];
        float x = loc_s[h][lp][0] * (float)Wl - 0.5f;
        float y = loc_s[h][lp][1] * (float)Hl - 0.5f;
        float x0f = floorf(x), y0f = floorf(y);
        float lx = x - x0f, ly = y - y0f;
        int x0 = (int)x0f, y0 = (int)y0f;
        int x1 = x0 + 1, y1 = y0 + 1;
        int vx0 = (x0 >= 0) & (x0 < Wl);
        int vx1 = (x1 >= 0) & (x1 < Wl);
        int vy0 = (y0 >= 0) & (y0 < Hl);
        int vy1 = (y1 >= 0) & (y1 < Hl);
        int x0c = min(max(x0, 0), Wl - 1);
        int x1c = min(max(x1, 0), Wl - 1);
        int y0c = min(max(y0, 0), Hl - 1);
        int y1c = min(max(y1, 0), Hl - 1);
        idx_s[h][lp][0] = start + y0c * Wl + x0c;
        idx_s[h][lp][1] = start + y0c * Wl + x1c;
        idx_s[h][lp][2] = start + y1c * Wl + x0c;
        idx_s[h][lp][3] = start + y1c * Wl + x1c;
        w_s[h][lp][0] = (vy0 & vx0) ? w * (1.f - lx) * (1.f - ly) : 0.f;
        w_s[h][lp][1] = (vy0 & vx1) ? w * lx * (1.f - ly) : 0.f;
        w_s[h][lp][2] = (vy1 & vx0) ? w * (1.f - lx) * ly : 0.f;
        w_s[h][lp][3] = (vy1 & vx1) ? w * lx * ly : 0.f;
    }
    __syncthreads();

    // ---- phase 4: gather + accumulate ----
    const int h = t >> 5;
    const float* vb = value + (size_t)frame * LEN_Q * 256 + t;  // channel == t
    float acc = 0.f;
    #pragma unroll
    for (int lp = 0; lp < 16; ++lp) {
        #pragma unroll
        for (int cr = 0; cr < 4; ++cr) {
            float w = w_s[h][lp][cr];
            int idx = idx_s[h][lp][cr];
            acc = fmaf(w, vb[(size_t)idx * 256], acc);
        }
    }
    samp[(size_t)row * 256 + t] = acc;
}

// ---------------------------------------------------------------------------
extern "C" void kernel_launch(void* const* d_in, const int* in_sizes, int n_in,
                              void* d_out, int out_size, void* d_ws, size_t ws_size,
                              hipStream_t stream)
{
    const float* query   = (const float*)d_in[0];
    const float* refpts  = (const float*)d_in[1];
    const float* inflat  = (const float*)d_in[2];
    const int*   spatial = (const int*)d_in[3];
    const int*   lsi     = (const int*)d_in[4];
    const float* Wv      = (const float*)d_in[5];
    const float* bv      = (const float*)d_in[6];
    const float* Woff    = (const float*)d_in[7];
    const float* boff    = (const float*)d_in[8];
    const float* Wattn   = (const float*)d_in[9];
    const float* battn   = (const float*)d_in[10];
    const float* Wout    = (const float*)d_in[11];
    const float* bout    = (const float*)d_in[12];
    float* out = (float*)d_out;

    float* ws = (float*)d_ws;
    float* value = ws;                                   // MTOT*256
    float* offb  = value + (size_t)MTOT * 256;           // MTOT*256
    float* attnb = offb  + (size_t)MTOT * 256;           // MTOT*128
    float* samp  = attnb + (size_t)MTOT * 128;           // MTOT*256

    dim3 blk(256);
    dim3 gFull(DMODEL / 64, (MTOT + 127) / 128);     // N=256 GEMMs
    dim3 gAttn(128 / 64, (MTOT + 127) / 128);        // N=128 GEMM

    hipLaunchKernelGGL(gemm_bias, gFull, blk, 0, stream,
                       inflat, Wv, bv, value, MTOT, 256, 256);
    hipLaunchKernelGGL(gemm_bias, gFull, blk, 0, stream,
                       query, Woff, boff, offb, MTOT, 256, 256);
    hipLaunchKernelGGL(gemm_bias, gAttn, blk, 0, stream,
                       query, Wattn, battn, attnb, MTOT, 128, 256);
    hipLaunchKernelGGL(sample_kernel, dim3(MTOT), blk, 0, stream,
                       value, offb, attnb, refpts, spatial, lsi, samp);
    hipLaunchKernelGGL(gemm_bias, gFull, blk, 0, stream,
                       samp, Wout, bout, out, MTOT, 256, 256);
}

// Round 2
// 262.778 us; speedup vs baseline: 2.0942x; 2.0942x over previous
//
#include <hip/hip_runtime.h>
#include <math.h>

#define LEN_Q 13294
#define NFRAMES 2
#define MTOT (LEN_Q * NFRAMES)   // 26588
#define DMODEL 256
#define HEADS 8
#define LEVELS 4
#define POINTS 4

typedef __attribute__((ext_vector_type(8))) short short8;
typedef __attribute__((ext_vector_type(4))) float f32x4;
typedef __attribute__((ext_vector_type(2))) unsigned int uint2v;
typedef __attribute__((ext_vector_type(4))) unsigned short ushort4v;

__device__ __forceinline__ unsigned short f2bf(float x) {
    unsigned u = __builtin_bit_cast(unsigned, x);
    unsigned r = (u + 0x7fffu + ((u >> 16) & 1u)) >> 16;
    return (unsigned short)r;
}
__device__ __forceinline__ float bf2f(unsigned short b) {
    return __builtin_bit_cast(float, (unsigned)b << 16);
}

// ---------------------------------------------------------------------------
// f32 -> bf16 elementwise convert (n divisible by 4 in our uses; guarded anyway)
// ---------------------------------------------------------------------------
__global__ __launch_bounds__(256) void cvt_bf16(const float* __restrict__ in,
                                                unsigned short* __restrict__ out, int n)
{
    int i = (blockIdx.x * 256 + threadIdx.x) * 4;
    if (i + 3 < n) {
        f32x4 v = *(const f32x4*)(in + i);
        ushort4v o;
        o.x = f2bf(v.x); o.y = f2bf(v.y); o.z = f2bf(v.z); o.w = f2bf(v.w);
        *(ushort4v*)(out + i) = o;
    } else {
        for (int j = i; j < n; ++j) out[j] = f2bf(in[j]);
    }
}

// ---------------------------------------------------------------------------
// B[K,N] f32 -> BT[N,K] bf16   (K == 256 here; one block per n)
// ---------------------------------------------------------------------------
__global__ __launch_bounds__(256) void transpose_cvt(const float* __restrict__ B,
                                                     unsigned short* __restrict__ BT,
                                                     int K, int N)
{
    int n = blockIdx.x;
    int k = threadIdx.x;
    if (k < K) BT[(size_t)n * K + k] = f2bf(B[(size_t)k * N + n]);
}

// ---------------------------------------------------------------------------
// bf16 MFMA GEMM: C[M,N] = A[M,K] @ BT[N,K]^T + bias
// One wave (64 thr) per 64x64 output tile; 4x4 grid of 16x16x32 MFMAs.
// A row-major bf16, BT row-major bf16 (i.e. B transposed). No LDS: fragment
// loads are 16B contiguous per lane for both operands; B reuse via L1/L2.
// ---------------------------------------------------------------------------
template <bool OUT_BF16>
__global__ __launch_bounds__(64) void gemm_mfma(
    const unsigned short* __restrict__ A,
    const unsigned short* __restrict__ BT,
    const float* __restrict__ bias,
    void* __restrict__ C,
    int M, int N, int K)
{
    const int L = threadIdx.x;
    const int m_base = blockIdx.y * 64;
    const int n_base = blockIdx.x * 64;
    const int lrow = L & 15;
    const int kq = (L >> 4) * 8;   // k-chunk base for this lane's quad

    f32x4 acc[4][4];
    #pragma unroll
    for (int i = 0; i < 4; ++i)
        #pragma unroll
        for (int j = 0; j < 4; ++j) acc[i][j] = (f32x4){0.f, 0.f, 0.f, 0.f};

    const unsigned short* arow[4];
    #pragma unroll
    for (int i = 0; i < 4; ++i) {
        int r = m_base + i * 16 + lrow;
        if (r > M - 1) r = M - 1;          // clamp: garbage rows guarded at store
        arow[i] = A + (size_t)r * K + kq;
    }
    const unsigned short* brow[4];
    #pragma unroll
    for (int j = 0; j < 4; ++j) {
        int r = n_base + j * 16 + lrow;    // N divides 64 -> always valid
        brow[j] = BT + (size_t)r * K + kq;
    }

    for (int k0 = 0; k0 < K; k0 += 32) {
        short8 af[4], bf[4];
        #pragma unroll
        for (int i = 0; i < 4; ++i) af[i] = *(const short8*)(arow[i] + k0);
        #pragma unroll
        for (int j = 0; j < 4; ++j) bf[j] = *(const short8*)(brow[j] + k0);
        #pragma unroll
        for (int i = 0; i < 4; ++i)
            #pragma unroll
            for (int j = 0; j < 4; ++j)
                acc[i][j] = __builtin_amdgcn_mfma_f32_16x16x32_bf16(af[i], bf[j], acc[i][j], 0, 0, 0);
    }

    // C/D layout: row m = (L>>4)*4 + r, col n = L&15  (per tile)
    const int mrow0 = (L >> 4) * 4;
    #pragma unroll
    for (int i = 0; i < 4; ++i) {
        #pragma unroll
        for (int r = 0; r < 4; ++r) {
            int m = m_base + i * 16 + mrow0 + r;
            if (m < M) {
                #pragma unroll
                for (int j = 0; j < 4; ++j) {
                    int n = n_base + j * 16 + lrow;
                    float v = acc[i][j][r] + bias[n];
                    if (OUT_BF16) ((unsigned short*)C)[(size_t)m * N + n] = f2bf(v);
                    else          ((float*)C)[(size_t)m * N + n] = v;
                }
            }
        }
    }
}

// ---------------------------------------------------------------------------
// Sampler: block = 256 thr = 4 waves, one row per wave (grid = MTOT/4 exact).
// Lane L of a wave: phases 1-3 build loc/softmax/corner tables in LDS, then
// gather phase: head h = L>>3, 4 channels (4L..4L+3) per lane, bf16x4 (8B)
// gathers -> 4x fewer vmem instrs than 1-chan-f32 layout, 1 cache line per
// head-row instead of 2.
// ---------------------------------------------------------------------------
__global__ __launch_bounds__(256) void sample2(
    const unsigned short* __restrict__ value,  // bf16 [MTOT,256]
    const unsigned short* __restrict__ off,    // bf16 [MTOT,256]
    const unsigned short* __restrict__ attn,   // bf16 [MTOT,128]
    const float* __restrict__ refpts,          // [LEN_Q, LEVELS, 2]
    const int*   __restrict__ spatial,         // [LEVELS,2] (H,W)
    const int*   __restrict__ lsi,             // [LEVELS]
    unsigned short* __restrict__ samp)         // bf16 [MTOT,256]
{
    const int w = threadIdx.x >> 6;
    const int L = threadIdx.x & 63;
    const int row = blockIdx.x * 4 + w;        // MTOT = 4*6647 exactly
    const int frame = row >= LEN_Q ? 1 : 0;
    const int q = row - frame * LEN_Q;

    __shared__ float attn_s[4][HEADS][16];
    __shared__ float loc_s[4][HEADS][16][2];
    __shared__ float w_s[4][HEADS][16][4];
    __shared__ int   idx_s[4][HEADS][16][4];

    // ---- phase 1: off -> loc, attn -> LDS ----
    {
        uint2v ov = *(const uint2v*)(off + (size_t)row * 256 + 4 * L);
        float o[4];
        o[0] = bf2f((unsigned short)(ov.x & 0xffffu));
        o[1] = bf2f((unsigned short)(ov.x >> 16));
        o[2] = bf2f((unsigned short)(ov.y & 0xffffu));
        o[3] = bf2f((unsigned short)(ov.y >> 16));
        #pragma unroll
        for (int i = 0; i < 4; ++i) {
            int t = 4 * L + i;
            int c = t & 1;
            int l = (t >> 3) & 3;
            int h = t >> 5;
            int lp = (t >> 1) & 15;
            float r = refpts[((size_t)q * LEVELS + l) * 2 + c];
            int dim = spatial[l * 2 + (c ^ 1)];   // c==0 -> W, c==1 -> H
            loc_s[w][h][lp][c] = r + o[i] / (float)dim;
        }
        unsigned av = *(const unsigned*)(attn + (size_t)row * 128 + 2 * L);
        int t0 = 2 * L;
        attn_s[w][t0 >> 4][t0 & 15] = bf2f((unsigned short)(av & 0xffffu));
        attn_s[w][(t0 + 1) >> 4][(t0 + 1) & 15] = bf2f((unsigned short)(av >> 16));
    }
    __syncthreads();

    // ---- phase 2: softmax per head ----
    if (L < 8) {
        float m = attn_s[w][L][0];
        #pragma unroll
        for (int i = 1; i < 16; ++i) m = fmaxf(m, attn_s[w][L][i]);
        float e[16]; float s = 0.f;
        #pragma unroll
        for (int i = 0; i < 16; ++i) { e[i] = __expf(attn_s[w][L][i] - m); s += e[i]; }
        float inv = 1.f / s;
        #pragma unroll
        for (int i = 0; i < 16; ++i) attn_s[w][L][i] = e[i] * inv;
    }
    __syncthreads();

    // ---- phase 3: corner idx + weight (2 entries per lane) ----
    #pragma unroll
    for (int i = 0; i < 2; ++i) {
        int e = 2 * L + i;
        int h = e >> 4;
        int lp = e & 15;
        int l = lp >> 2;
        int Hl = spatial[l * 2], Wl = spatial[l * 2 + 1];
        int start = lsi[l];
        float wt = attn_s[w][h][lp];
        float x = loc_s[w][h][lp][0] * (float)Wl - 0.5f;
        float y = loc_s[w][h][lp][1] * (float)Hl - 0.5f;
        float x0f = floorf(x), y0f = floorf(y);
        float lx = x - x0f, ly = y - y0f;
        int x0 = (int)x0f, y0 = (int)y0f;
        int x1 = x0 + 1, y1 = y0 + 1;
        int vx0 = (x0 >= 0) & (x0 < Wl);
        int vx1 = (x1 >= 0) & (x1 < Wl);
        int vy0 = (y0 >= 0) & (y0 < Hl);
        int vy1 = (y1 >= 0) & (y1 < Hl);
        int x0c = min(max(x0, 0), Wl - 1);
        int x1c = min(max(x1, 0), Wl - 1);
        int y0c = min(max(y0, 0), Hl - 1);
        int y1c = min(max(y1, 0), Hl - 1);
        idx_s[w][h][lp][0] = start + y0c * Wl + x0c;
        idx_s[w][h][lp][1] = start + y0c * Wl + x1c;
        idx_s[w][h][lp][2] = start + y1c * Wl + x0c;
        idx_s[w][h][lp][3] = start + y1c * Wl + x1c;
        w_s[w][h][lp][0] = (vy0 & vx0) ? wt * (1.f - lx) * (1.f - ly) : 0.f;
        w_s[w][h][lp][1] = (vy0 & vx1) ? wt * lx * (1.f - ly) : 0.f;
        w_s[w][h][lp][2] = (vy1 & vx0) ? wt * (1.f - lx) * ly : 0.f;
        w_s[w][h][lp][3] = (vy1 & vx1) ? wt * lx * ly : 0.f;
    }
    __syncthreads();

    // ---- phase 4: gather (bf16x4 per lane) ----
    const int h = L >> 3;
    const unsigned short* vbase = value + (size_t)frame * LEN_Q * 256 + 4 * L;
    float a0 = 0.f, a1 = 0.f, a2 = 0.f, a3 = 0.f;
    #pragma unroll
    for (int lp = 0; lp < 16; ++lp) {
        #pragma unroll
        for (int cr = 0; cr < 4; ++cr) {
            float wt = w_s[w][h][lp][cr];
            int idx = idx_s[w][h][lp][cr];
            uint2v v = *(const uint2v*)(vbase + (size_t)idx * 256);
            a0 = fmaf(wt, __builtin_bit_cast(float, v.x << 16), a0);
            a1 = fmaf(wt, __builtin_bit_cast(float, v.x & 0xffff0000u), a1);
            a2 = fmaf(wt, __builtin_bit_cast(float, v.y << 16), a2);
            a3 = fmaf(wt, __builtin_bit_cast(float, v.y & 0xffff0000u), a3);
        }
    }
    ushort4v o;
    o.x = f2bf(a0); o.y = f2bf(a1); o.z = f2bf(a2); o.w = f2bf(a3);
    *(ushort4v*)(samp + (size_t)row * 256 + 4 * L) = o;
}

// ---------------------------------------------------------------------------
extern "C" void kernel_launch(void* const* d_in, const int* in_sizes, int n_in,
                              void* d_out, int out_size, void* d_ws, size_t ws_size,
                              hipStream_t stream)
{
    const float* query   = (const float*)d_in[0];
    const float* refpts  = (const float*)d_in[1];
    const float* inflat  = (const float*)d_in[2];
    const int*   spatial = (const int*)d_in[3];
    const int*   lsi     = (const int*)d_in[4];
    const float* Wv      = (const float*)d_in[5];
    const float* bv      = (const float*)d_in[6];
    const float* Woff    = (const float*)d_in[7];
    const float* boff    = (const float*)d_in[8];
    const float* Wattn   = (const float*)d_in[9];
    const float* battn   = (const float*)d_in[10];
    const float* Wout    = (const float*)d_in[11];
    const float* bout    = (const float*)d_in[12];
    float* out = (float*)d_out;

    unsigned short* ws = (unsigned short*)d_ws;
    const size_t MR = (size_t)MTOT * 256;
    unsigned short* q16    = ws;                 // MTOT*256
    unsigned short* in16   = q16 + MR;           // MTOT*256
    unsigned short* v16    = in16 + MR;          // MTOT*256
    unsigned short* off16  = v16 + MR;           // MTOT*256
    unsigned short* at16   = off16 + MR;         // MTOT*128
    unsigned short* samp16 = at16 + (size_t)MTOT * 128;  // MTOT*256
    unsigned short* wvT    = samp16 + MR;        // 256*256
    unsigned short* woffT  = wvT + 65536;        // 256*256
    unsigned short* wattnT = woffT + 65536;      // 128*256
    unsigned short* woutT  = wattnT + 32768;     // 256*256

    const int nElem = MTOT * 256;                // 6,806,528 (div by 1024)
    dim3 blk256(256);

    hipLaunchKernelGGL(cvt_bf16, dim3(nElem / 1024), blk256, 0, stream, query,  q16,  nElem);
    hipLaunchKernelGGL(cvt_bf16, dim3(nElem / 1024), blk256, 0, stream, inflat, in16, nElem);
    hipLaunchKernelGGL(transpose_cvt, dim3(256), blk256, 0, stream, Wv,    wvT,    256, 256);
    hipLaunchKernelGGL(transpose_cvt, dim3(256), blk256, 0, stream, Woff,  woffT,  256, 256);
    hipLaunchKernelGGL(transpose_cvt, dim3(128), blk256, 0, stream, Wattn, wattnT, 256, 128);
    hipLaunchKernelGGL(transpose_cvt, dim3(256), blk256, 0, stream, Wout,  woutT,  256, 256);

    const int mTiles = (MTOT + 63) / 64;         // 416
    hipLaunchKernelGGL((gemm_mfma<true>),  dim3(4, mTiles), dim3(64), 0, stream,
                       in16, wvT, bv, (void*)v16, MTOT, 256, 256);
    hipLaunchKernelGGL((gemm_mfma<true>),  dim3(4, mTiles), dim3(64), 0, stream,
                       q16, woffT, boff, (void*)off16, MTOT, 256, 256);
    hipLaunchKernelGGL((gemm_mfma<true>),  dim3(2, mTiles), dim3(64), 0, stream,
                       q16, wattnT, battn, (void*)at16, MTOT, 128, 256);

    hipLaunchKernelGGL(sample2, dim3(MTOT / 4), blk256, 0, stream,
                       v16, off16, at16, refpts, spatial, lsi, samp16);

    hipLaunchKernelGGL((gemm_mfma<false>), dim3(4, mTiles), dim3(64), 0, stream,
                       samp16, woutT, bout, d_out, MTOT, 256, 256);
}